// Round 3
// baseline (6684.811 us; speedup 1.0000x reference)
//
#include <hip/hip_runtime.h>
#include <hip/hip_bf16.h>

#define H 128
#define NN 50000
#define NE 500000
#define NB 64
#define NSTEPS 3
#define LROW 136  // 128 + 8 pad

typedef __bf16 bf16x8 __attribute__((ext_vector_type(8)));
typedef float f32x4 __attribute__((ext_vector_type(4)));

__device__ __forceinline__ f32x4 mfma16(bf16x8 a, bf16x8 b, f32x4 c) {
  return __builtin_amdgcn_mfma_f32_16x16x32_bf16(a, b, c, 0, 0, 0);
}
__device__ __forceinline__ float sigm(float x) { return 1.f / (1.f + __expf(-x)); }
__device__ __forceinline__ float tanh_(float x) { return 1.f - 2.f / (1.f + __expf(2.f * x)); }
__device__ __forceinline__ bf16x8 cvt8s(float4 lo, float4 hi, float s) {
  bf16x8 v;
  v[0] = (__bf16)(lo.x * s); v[1] = (__bf16)(lo.y * s);
  v[2] = (__bf16)(lo.z * s); v[3] = (__bf16)(lo.w * s);
  v[4] = (__bf16)(hi.x * s); v[5] = (__bf16)(hi.y * s);
  v[6] = (__bf16)(hi.z * s); v[7] = (__bf16)(hi.w * s);
  return v;
}

// dtype-overloaded fragment load / scalar load / scalar store
__device__ __forceinline__ bf16x8 g8(const __bf16* p) { return *reinterpret_cast<const bf16x8*>(p); }
__device__ __forceinline__ bf16x8 g8(const float* p) {
  float4 lo = *(const float4*)p, hi = *(const float4*)(p + 4);
  return cvt8s(lo, hi, 1.f);
}
__device__ __forceinline__ float ldf(const __bf16* p) { return (float)*p; }
__device__ __forceinline__ float ldf(const float* p) { return *p; }
__device__ __forceinline__ void stf(__bf16* p, float v) { *p = (__bf16)v; }
__device__ __forceinline__ void stf(float* p, float v) { *p = v; }
__device__ __forceinline__ bf16x8 zero8() {
  bf16x8 v;
#pragma unroll
  for (int i = 0; i < 8; ++i) v[i] = (__bf16)0.f;
  return v;
}

// ---- dtype detector: bf16 data ~N(0,1) is always "sane"; f32 data read as
// bf16 halves yields wild exponents / NaN patterns with near-certainty. ----
__global__ void detect_kernel(const unsigned short* __restrict__ xraw, int* __restrict__ flag) {
  bool insane = false;
  for (int i = threadIdx.x; i < 1024; i += 64) {
    unsigned int u = ((unsigned int)xraw[i]) << 16;
    float v = __uint_as_float(u);
    if (!isfinite(v) || fabsf(v) > 1e4f) insane = true;
  }
  unsigned long long m = __ballot(insane);
  if (threadIdx.x == 0) flag[0] = (m != 0ULL) ? 1 : 0;
}

__global__ void count_kernel(const int* __restrict__ dst, const int* __restrict__ batch,
                             int* __restrict__ dcnt, int* __restrict__ ncnt) {
  int i = blockIdx.x * 256 + threadIdx.x;
  if (i < NE) atomicAdd(&dcnt[dst[i]], 1);
  if (i < NN) atomicAdd(&ncnt[batch[i]], 1);
}

// ---------------- edge model body ----------------
template <typename T>
__device__ __forceinline__ void edge_body(
    const T* x, const int* ei, T* ea, const T* u, const int* batch,
    const T* w1, const T* b1, const T* w2, const T* b2,
    const T* wih, const T* whh, const T* bih, const T* bhh,
    float* agg, int ws_ok, __bf16* myl, int wave, int lane) {
  const int* src = ei;
  const int* dst = ei + NE;
  const int lm = lane & 15, quad = lane >> 4;
  const long base = ((long)blockIdx.x * 4 + wave) * 32;

  long tA0 = base + lm;      const int eA0 = (int)(tA0 < NE ? tA0 : NE - 1);
  long tA1 = base + 16 + lm; const int eA1 = (int)(tA1 < NE ? tA1 : NE - 1);
  const int s0 = src[eA0], s1 = src[eA1];
  const int d0 = dst[eA0], d1 = dst[eA1];
  const int g0 = batch[s0], g1 = batch[s1];

  // ---- layer 1: K = 512 over 4 gathered segments ----
  f32x4 acc[8][2] = {};
  bf16x8 ah0[4], ah1[4];
  for (int seg = 0; seg < 4; ++seg) {
    const T *p0, *p1;
    if (seg == 0)      { p0 = x + s0 * H;   p1 = x + s1 * H; }
    else if (seg == 1) { p0 = x + d0 * H;   p1 = x + d1 * H; }
    else if (seg == 2) { p0 = ea + eA0 * H; p1 = ea + eA1 * H; }
    else               { p0 = u + g0 * H;   p1 = u + g1 * H; }
#pragma unroll
    for (int ss = 0; ss < 4; ++ss) {
      const int kk = ss * 32 + quad * 8;
      bf16x8 a0 = g8(p0 + kk), a1 = g8(p1 + kk);
      if (seg == 2) { ah0[ss] = a0; ah1[ss] = a1; }
#pragma unroll
      for (int n = 0; n < 8; ++n) {
        bf16x8 bf = g8(w1 + (n * 16 + lm) * 512 + seg * 128 + kk);
        acc[n][0] = mfma16(a0, bf, acc[n][0]);
        acc[n][1] = mfma16(a1, bf, acc[n][1]);
      }
    }
  }
#pragma unroll
  for (int n = 0; n < 8; ++n) {
    const float bb = ldf(b1 + n * 16 + lm);
#pragma unroll
    for (int sub = 0; sub < 2; ++sub)
#pragma unroll
      for (int r = 0; r < 4; ++r) {
        float v = fmaxf(acc[n][sub][r] + bb, 0.f);
        myl[(sub * 16 + quad * 4 + r) * LROW + n * 16 + lm] = (__bf16)v;
      }
  }
  __syncthreads();
  // ---- layer 2 ----
  bf16x8 a20[4], a21[4];
#pragma unroll
  for (int ss = 0; ss < 4; ++ss) {
    a20[ss] = g8(myl + lm * LROW + ss * 32 + quad * 8);
    a21[ss] = g8(myl + (16 + lm) * LROW + ss * 32 + quad * 8);
  }
  f32x4 acc2[8][2] = {};
#pragma unroll
  for (int ss = 0; ss < 4; ++ss) {
    const int kk = ss * 32 + quad * 8;
#pragma unroll
    for (int n = 0; n < 8; ++n) {
      bf16x8 bf = g8(w2 + (n * 16 + lm) * H + kk);
      acc2[n][0] = mfma16(a20[ss], bf, acc2[n][0]);
      acc2[n][1] = mfma16(a21[ss], bf, acc2[n][1]);
    }
  }
  __syncthreads();
#pragma unroll
  for (int n = 0; n < 8; ++n) {
    const float bb = ldf(b2 + n * 16 + lm);
#pragma unroll
    for (int sub = 0; sub < 2; ++sub)
#pragma unroll
      for (int r = 0; r < 4; ++r)
        myl[(sub * 16 + quad * 4 + r) * LROW + n * 16 + lm] = (__bf16)(acc2[n][sub][r] + bb);
  }
  __syncthreads();
  // ---- GRU ----
  bf16x8 ao0[4], ao1[4];
#pragma unroll
  for (int ss = 0; ss < 4; ++ss) {
    ao0[ss] = g8(myl + lm * LROW + ss * 32 + quad * 8);
    ao1[ss] = g8(myl + (16 + lm) * LROW + ss * 32 + quad * 8);
  }
  int erow[2][4], drow[2][4];
#pragma unroll
  for (int sub = 0; sub < 2; ++sub)
#pragma unroll
    for (int r = 0; r < 4; ++r) {
      long e = base + sub * 16 + quad * 4 + r;
      int ec = (int)(e < NE ? e : NE - 1);
      erow[sub][r] = ec;
      drow[sub][r] = dst[ec];
    }
#pragma unroll 2
  for (int n = 0; n < 8; ++n) {
    f32x4 air[2] = {}, aiz[2] = {}, aig[2] = {};
    f32x4 ahr[2] = {}, ahz[2] = {}, ahg[2] = {};
    const int wr0 = (n * 16 + lm) * H;
#pragma unroll
    for (int ss = 0; ss < 4; ++ss) {
      const int kk = ss * 32 + quad * 8;
      bf16x8 wr = g8(wih + wr0 + kk);
      bf16x8 wz = g8(wih + wr0 + 128 * H + kk);
      bf16x8 wg = g8(wih + wr0 + 256 * H + kk);
      air[0] = mfma16(ao0[ss], wr, air[0]); air[1] = mfma16(ao1[ss], wr, air[1]);
      aiz[0] = mfma16(ao0[ss], wz, aiz[0]); aiz[1] = mfma16(ao1[ss], wz, aiz[1]);
      aig[0] = mfma16(ao0[ss], wg, aig[0]); aig[1] = mfma16(ao1[ss], wg, aig[1]);
      bf16x8 vr = g8(whh + wr0 + kk);
      bf16x8 vz = g8(whh + wr0 + 128 * H + kk);
      bf16x8 vg = g8(whh + wr0 + 256 * H + kk);
      ahr[0] = mfma16(ah0[ss], vr, ahr[0]); ahr[1] = mfma16(ah1[ss], vr, ahr[1]);
      ahz[0] = mfma16(ah0[ss], vz, ahz[0]); ahz[1] = mfma16(ah1[ss], vz, ahz[1]);
      ahg[0] = mfma16(ah0[ss], vg, ahg[0]); ahg[1] = mfma16(ah1[ss], vg, ahg[1]);
    }
    const int c = n * 16 + lm;
    const float bir = ldf(bih + c), biz = ldf(bih + c + 128), big = ldf(bih + c + 256);
    const float bhr = ldf(bhh + c), bhz = ldf(bhh + c + 128), bhg = ldf(bhh + c + 256);
#pragma unroll
    for (int sub = 0; sub < 2; ++sub)
#pragma unroll
      for (int r = 0; r < 4; ++r) {
        float rg = sigm(air[sub][r] + bir + ahr[sub][r] + bhr);
        float zg = sigm(aiz[sub][r] + biz + ahz[sub][r] + bhz);
        float ng = tanh_(aig[sub][r] + big + rg * (ahg[sub][r] + bhg));
        int e = erow[sub][r];
        float hold = ldf(ea + (size_t)e * H + c);
        float hnew = (1.f - zg) * ng + zg * hold;
        if (base + sub * 16 + quad * 4 + r < NE) {
          stf(ea + (size_t)e * H + c, hnew);
          if (ws_ok) atomicAdd(&agg[drow[sub][r] * H + c], hnew);
        }
      }
  }
}

__global__ __launch_bounds__(256, 2) void edge_kernel(
    const void* x, const int* ei, void* ea, const void* u, const int* batch,
    const void* w1, const void* b1, const void* w2, const void* b2,
    const void* wih, const void* whh, const void* bih, const void* bhh,
    float* agg, const int* flag, int ws_ok) {
  __shared__ __bf16 lds[4][32 * LROW];
  const int wave = threadIdx.x >> 6, lane = threadIdx.x & 63;
  const int dt = flag[0];
  if (dt) {
    edge_body<float>((const float*)x, ei, (float*)ea, (const float*)u, batch,
                     (const float*)w1, (const float*)b1, (const float*)w2, (const float*)b2,
                     (const float*)wih, (const float*)whh, (const float*)bih, (const float*)bhh,
                     agg, ws_ok, lds[wave], wave, lane);
  } else {
    edge_body<__bf16>((const __bf16*)x, ei, (__bf16*)ea, (const __bf16*)u, batch,
                      (const __bf16*)w1, (const __bf16*)b1, (const __bf16*)w2, (const __bf16*)b2,
                      (const __bf16*)wih, (const __bf16*)whh, (const __bf16*)bih, (const __bf16*)bhh,
                      agg, ws_ok, lds[wave], wave, lane);
  }
}

// ---------------- node model body ----------------
template <typename T>
__device__ __forceinline__ void node_body(
    T* x, const T* u, const int* batch, const float* agg, const int* dcnt,
    const T* w1, const T* b1, const T* w2, const T* b2,
    const T* wih, const T* whh, const T* bih, const T* bhh,
    float* xsum, int ws_ok, __bf16* myl, int wave, int lane) {
  const int lm = lane & 15, quad = lane >> 4;
  const long base = ((long)blockIdx.x * 4 + wave) * 32;

  long tA0 = base + lm;      const int iA0 = (int)(tA0 < NN ? tA0 : NN - 1);
  long tA1 = base + 16 + lm; const int iA1 = (int)(tA1 < NN ? tA1 : NN - 1);
  const int g0 = batch[iA0], g1 = batch[iA1];
  const float inv0 = ws_ok ? 1.f / (float)max(dcnt[iA0], 1) : 1.f;
  const float inv1 = ws_ok ? 1.f / (float)max(dcnt[iA1], 1) : 1.f;

  f32x4 acc[8][2] = {};
  bf16x8 ah0[4], ah1[4];
  for (int seg = 0; seg < 3; ++seg) {
#pragma unroll
    for (int ss = 0; ss < 4; ++ss) {
      const int kk = ss * 32 + quad * 8;
      bf16x8 a0, a1;
      if (seg == 0) {
        a0 = g8(x + iA0 * H + kk); a1 = g8(x + iA1 * H + kk);
        ah0[ss] = a0; ah1[ss] = a1;
      } else if (seg == 1) {
        if (ws_ok) {
          float4 lo0 = *(const float4*)(agg + iA0 * H + kk);
          float4 hi0 = *(const float4*)(agg + iA0 * H + kk + 4);
          float4 lo1 = *(const float4*)(agg + iA1 * H + kk);
          float4 hi1 = *(const float4*)(agg + iA1 * H + kk + 4);
          a0 = cvt8s(lo0, hi0, inv0); a1 = cvt8s(lo1, hi1, inv1);
        } else {
          a0 = zero8(); a1 = zero8();
        }
      } else {
        a0 = g8(u + g0 * H + kk); a1 = g8(u + g1 * H + kk);
      }
#pragma unroll
      for (int n = 0; n < 8; ++n) {
        bf16x8 bf = g8(w1 + (n * 16 + lm) * 384 + seg * 128 + kk);
        acc[n][0] = mfma16(a0, bf, acc[n][0]);
        acc[n][1] = mfma16(a1, bf, acc[n][1]);
      }
    }
  }
#pragma unroll
  for (int n = 0; n < 8; ++n) {
    const float bb = ldf(b1 + n * 16 + lm);
#pragma unroll
    for (int sub = 0; sub < 2; ++sub)
#pragma unroll
      for (int r = 0; r < 4; ++r) {
        float v = fmaxf(acc[n][sub][r] + bb, 0.f);
        myl[(sub * 16 + quad * 4 + r) * LROW + n * 16 + lm] = (__bf16)v;
      }
  }
  __syncthreads();
  bf16x8 a20[4], a21[4];
#pragma unroll
  for (int ss = 0; ss < 4; ++ss) {
    a20[ss] = g8(myl + lm * LROW + ss * 32 + quad * 8);
    a21[ss] = g8(myl + (16 + lm) * LROW + ss * 32 + quad * 8);
  }
  f32x4 acc2[8][2] = {};
#pragma unroll
  for (int ss = 0; ss < 4; ++ss) {
    const int kk = ss * 32 + quad * 8;
#pragma unroll
    for (int n = 0; n < 8; ++n) {
      bf16x8 bf = g8(w2 + (n * 16 + lm) * H + kk);
      acc2[n][0] = mfma16(a20[ss], bf, acc2[n][0]);
      acc2[n][1] = mfma16(a21[ss], bf, acc2[n][1]);
    }
  }
  __syncthreads();
#pragma unroll
  for (int n = 0; n < 8; ++n) {
    const float bb = ldf(b2 + n * 16 + lm);
#pragma unroll
    for (int sub = 0; sub < 2; ++sub)
#pragma unroll
      for (int r = 0; r < 4; ++r)
        myl[(sub * 16 + quad * 4 + r) * LROW + n * 16 + lm] = (__bf16)(acc2[n][sub][r] + bb);
  }
  __syncthreads();
  bf16x8 ao0[4], ao1[4];
#pragma unroll
  for (int ss = 0; ss < 4; ++ss) {
    ao0[ss] = g8(myl + lm * LROW + ss * 32 + quad * 8);
    ao1[ss] = g8(myl + (16 + lm) * LROW + ss * 32 + quad * 8);
  }
  int irow[2][4], brow[2][4];
#pragma unroll
  for (int sub = 0; sub < 2; ++sub)
#pragma unroll
    for (int r = 0; r < 4; ++r) {
      long i = base + sub * 16 + quad * 4 + r;
      int ic = (int)(i < NN ? i : NN - 1);
      irow[sub][r] = ic;
      brow[sub][r] = batch[ic];
    }
#pragma unroll 2
  for (int n = 0; n < 8; ++n) {
    f32x4 air[2] = {}, aiz[2] = {}, aig[2] = {};
    f32x4 ahr[2] = {}, ahz[2] = {}, ahg[2] = {};
    const int wr0 = (n * 16 + lm) * H;
#pragma unroll
    for (int ss = 0; ss < 4; ++ss) {
      const int kk = ss * 32 + quad * 8;
      bf16x8 wr = g8(wih + wr0 + kk);
      bf16x8 wz = g8(wih + wr0 + 128 * H + kk);
      bf16x8 wg = g8(wih + wr0 + 256 * H + kk);
      air[0] = mfma16(ao0[ss], wr, air[0]); air[1] = mfma16(ao1[ss], wr, air[1]);
      aiz[0] = mfma16(ao0[ss], wz, aiz[0]); aiz[1] = mfma16(ao1[ss], wz, aiz[1]);
      aig[0] = mfma16(ao0[ss], wg, aig[0]); aig[1] = mfma16(ao1[ss], wg, aig[1]);
      bf16x8 vr = g8(whh + wr0 + kk);
      bf16x8 vz = g8(whh + wr0 + 128 * H + kk);
      bf16x8 vg = g8(whh + wr0 + 256 * H + kk);
      ahr[0] = mfma16(ah0[ss], vr, ahr[0]); ahr[1] = mfma16(ah1[ss], vr, ahr[1]);
      ahz[0] = mfma16(ah0[ss], vz, ahz[0]); ahz[1] = mfma16(ah1[ss], vz, ahz[1]);
      ahg[0] = mfma16(ah0[ss], vg, ahg[0]); ahg[1] = mfma16(ah1[ss], vg, ahg[1]);
    }
    const int c = n * 16 + lm;
    const float bir = ldf(bih + c), biz = ldf(bih + c + 128), big = ldf(bih + c + 256);
    const float bhr = ldf(bhh + c), bhz = ldf(bhh + c + 128), bhg = ldf(bhh + c + 256);
#pragma unroll
    for (int sub = 0; sub < 2; ++sub)
#pragma unroll
      for (int r = 0; r < 4; ++r) {
        float rg = sigm(air[sub][r] + bir + ahr[sub][r] + bhr);
        float zg = sigm(aiz[sub][r] + biz + ahz[sub][r] + bhz);
        float ng = tanh_(aig[sub][r] + big + rg * (ahg[sub][r] + bhg));
        int i = irow[sub][r];
        float hold = ldf(x + (size_t)i * H + c);
        float hnew = (1.f - zg) * ng + zg * hold;
        if (base + sub * 16 + quad * 4 + r < NN) {
          stf(x + (size_t)i * H + c, hnew);
          if (ws_ok) atomicAdd(&xsum[brow[sub][r] * H + c], hnew);
        }
      }
  }
}

__global__ __launch_bounds__(256, 2) void node_kernel(
    void* x, const void* u, const int* batch, const float* agg, const int* dcnt,
    const void* w1, const void* b1, const void* w2, const void* b2,
    const void* wih, const void* whh, const void* bih, const void* bhh,
    float* xsum, const int* flag, int ws_ok) {
  __shared__ __bf16 lds[4][32 * LROW];
  const int wave = threadIdx.x >> 6, lane = threadIdx.x & 63;
  const int dt = flag[0];
  if (dt) {
    node_body<float>((float*)x, (const float*)u, batch, agg, dcnt,
                     (const float*)w1, (const float*)b1, (const float*)w2, (const float*)b2,
                     (const float*)wih, (const float*)whh, (const float*)bih, (const float*)bhh,
                     xsum, ws_ok, lds[wave], wave, lane);
  } else {
    node_body<__bf16>((__bf16*)x, (const __bf16*)u, batch, agg, dcnt,
                      (const __bf16*)w1, (const __bf16*)b1, (const __bf16*)w2, (const __bf16*)b2,
                      (const __bf16*)wih, (const __bf16*)whh, (const __bf16*)bih, (const __bf16*)bhh,
                      xsum, ws_ok, lds[wave], wave, lane);
  }
}

// ---------------- global model body ----------------
template <typename T>
__device__ __forceinline__ void glob_body(
    T* u, const float* xsum, const int* ncnt,
    const T* w1, const T* b1, const T* w2, const T* b2,
    const T* wih, const T* whh, const T* bih, const T* bhh,
    T* out, int t, int ws_ok, __bf16* myl, int wave, int lane) {
  const int lm = lane & 15, quad = lane >> 4;
  const int row = wave * 16 + lm;
  const float inv = ws_ok ? 1.f / fmaxf((float)ncnt[row], 1.f) : 1.f;

  f32x4 acc[8] = {};
  bf16x8 ah[4];
#pragma unroll
  for (int seg = 0; seg < 2; ++seg) {
#pragma unroll
    for (int ss = 0; ss < 4; ++ss) {
      const int kk = ss * 32 + quad * 8;
      bf16x8 a;
      if (seg == 0) {
        a = g8(u + row * H + kk);
        ah[ss] = a;
      } else if (ws_ok) {
        float4 lo = *(const float4*)(xsum + row * H + kk);
        float4 hi = *(const float4*)(xsum + row * H + kk + 4);
        a = cvt8s(lo, hi, inv);
      } else {
        a = zero8();
      }
#pragma unroll
      for (int n = 0; n < 8; ++n) {
        bf16x8 bf = g8(w1 + (n * 16 + lm) * 256 + seg * 128 + kk);
        acc[n] = mfma16(a, bf, acc[n]);
      }
    }
  }
#pragma unroll
  for (int n = 0; n < 8; ++n) {
    const float bb = ldf(b1 + n * 16 + lm);
#pragma unroll
    for (int r = 0; r < 4; ++r)
      myl[(quad * 4 + r) * LROW + n * 16 + lm] = (__bf16)fmaxf(acc[n][r] + bb, 0.f);
  }
  __syncthreads();
  bf16x8 a2[4];
#pragma unroll
  for (int ss = 0; ss < 4; ++ss) a2[ss] = g8(myl + lm * LROW + ss * 32 + quad * 8);
  f32x4 acc2[8] = {};
#pragma unroll
  for (int ss = 0; ss < 4; ++ss) {
    const int kk = ss * 32 + quad * 8;
#pragma unroll
    for (int n = 0; n < 8; ++n) {
      bf16x8 bf = g8(w2 + (n * 16 + lm) * H + kk);
      acc2[n] = mfma16(a2[ss], bf, acc2[n]);
    }
  }
  __syncthreads();
#pragma unroll
  for (int n = 0; n < 8; ++n) {
    const float bb = ldf(b2 + n * 16 + lm);
#pragma unroll
    for (int r = 0; r < 4; ++r)
      myl[(quad * 4 + r) * LROW + n * 16 + lm] = (__bf16)(acc2[n][r] + bb);
  }
  __syncthreads();
  bf16x8 ao[4];
#pragma unroll
  for (int ss = 0; ss < 4; ++ss) ao[ss] = g8(myl + lm * LROW + ss * 32 + quad * 8);
  for (int n = 0; n < 8; ++n) {
    f32x4 air = {}, aiz = {}, aig = {}, ahr = {}, ahz = {}, ahg = {};
    const int wr0 = (n * 16 + lm) * H;
#pragma unroll
    for (int ss = 0; ss < 4; ++ss) {
      const int kk = ss * 32 + quad * 8;
      air = mfma16(ao[ss], g8(wih + wr0 + kk), air);
      aiz = mfma16(ao[ss], g8(wih + wr0 + 128 * H + kk), aiz);
      aig = mfma16(ao[ss], g8(wih + wr0 + 256 * H + kk), aig);
      ahr = mfma16(ah[ss], g8(whh + wr0 + kk), ahr);
      ahz = mfma16(ah[ss], g8(whh + wr0 + 128 * H + kk), ahz);
      ahg = mfma16(ah[ss], g8(whh + wr0 + 256 * H + kk), ahg);
    }
    const int c = n * 16 + lm;
    const float bir = ldf(bih + c), biz = ldf(bih + c + 128), big = ldf(bih + c + 256);
    const float bhr = ldf(bhh + c), bhz = ldf(bhh + c + 128), bhg = ldf(bhh + c + 256);
#pragma unroll
    for (int r = 0; r < 4; ++r) {
      const int rowC = wave * 16 + quad * 4 + r;
      float rg = sigm(air[r] + bir + ahr[r] + bhr);
      float zg = sigm(aiz[r] + biz + ahz[r] + bhz);
      float ng = tanh_(aig[r] + big + rg * (ahg[r] + bhg));
      float hold = ldf(u + rowC * H + c);
      float hnew = (1.f - zg) * ng + zg * hold;
      stf(u + rowC * H + c, hnew);
      stf(out + (rowC * NSTEPS + t) * H + c, hnew);
    }
  }
}

__global__ __launch_bounds__(256) void glob_kernel(
    void* u, const float* xsum, const int* ncnt,
    const void* w1, const void* b1, const void* w2, const void* b2,
    const void* wih, const void* whh, const void* bih, const void* bhh,
    void* out, int t, const int* flag, int ws_ok) {
  __shared__ __bf16 lds[4][16 * LROW];
  const int wave = threadIdx.x >> 6, lane = threadIdx.x & 63;
  const int dt = flag[0];
  if (dt) {
    glob_body<float>((float*)u, xsum, ncnt,
                     (const float*)w1, (const float*)b1, (const float*)w2, (const float*)b2,
                     (const float*)wih, (const float*)whh, (const float*)bih, (const float*)bhh,
                     (float*)out, t, ws_ok, lds[wave], wave, lane);
  } else {
    glob_body<__bf16>((__bf16*)u, xsum, ncnt,
                      (const __bf16*)w1, (const __bf16*)b1, (const __bf16*)w2, (const __bf16*)b2,
                      (const __bf16*)wih, (const __bf16*)whh, (const __bf16*)bih, (const __bf16*)bhh,
                      (__bf16*)out, t, ws_ok, lds[wave], wave, lane);
  }
}

extern "C" void kernel_launch(void* const* d_in, const int* in_sizes, int n_in,
                              void* d_out, int out_size, void* d_ws, size_t ws_size,
                              hipStream_t stream) {
  void* x = d_in[0];
  const int* ei = (const int*)d_in[1];
  void* ea = d_in[2];
  void* u = d_in[3];
  const int* batch = (const int*)d_in[4];

  char* ws = (char*)d_ws;
  int* flag = (int*)ws;                                         // 16 B
  float* agg = (float*)(ws + 16);                               // NN*H f32
  float* xsum = (float*)(ws + 16 + (size_t)NN * H * 4);         // NB*H f32
  int* dcnt = (int*)(ws + 16 + (size_t)NN * H * 4 + (size_t)NB * H * 4);
  int* ncnt = dcnt + NN;
  const size_t need = 16 + (size_t)NN * H * 4 + (size_t)NB * H * 4 + (size_t)(NN + NB) * 4;
  const int ws_ok = (ws_size >= need) ? 1 : 0;

  detect_kernel<<<1, 64, 0, stream>>>((const unsigned short*)x, flag);
  if (ws_ok) {
    hipMemsetAsync(dcnt, 0, (NN + NB) * sizeof(int), stream);
    count_kernel<<<(NE + 255) / 256, 256, 0, stream>>>(ei + NE, batch, dcnt, ncnt);
  }

  for (int t = 0; t < NSTEPS; ++t) {
    if (ws_ok) {
      hipMemsetAsync(agg, 0, (size_t)NN * H * sizeof(float), stream);
      hipMemsetAsync(xsum, 0, (size_t)NB * H * sizeof(float), stream);
    }
    edge_kernel<<<(NE + 127) / 128, 256, 0, stream>>>(
        x, ei, ea, u, batch, d_in[5], d_in[6], d_in[7], d_in[8],
        d_in[17], d_in[18], d_in[19], d_in[20], agg, flag, ws_ok);
    node_kernel<<<(NN + 127) / 128, 256, 0, stream>>>(
        x, u, batch, agg, dcnt, d_in[9], d_in[10], d_in[11], d_in[12],
        d_in[21], d_in[22], d_in[23], d_in[24], xsum, flag, ws_ok);
    glob_kernel<<<1, 256, 0, stream>>>(
        u, xsum, ncnt, d_in[13], d_in[14], d_in[15], d_in[16],
        d_in[25], d_in[26], d_in[27], d_in[28], d_out, t, flag, ws_ok);
  }
}

// Round 4
// 4594.486 us; speedup vs baseline: 1.4550x; 1.4550x over previous
//
#include <hip/hip_runtime.h>
#include <hip/hip_bf16.h>

#define H 128
#define NN 50000
#define NE 500000
#define NB 64
#define NSTEPS 3
#define LROW 136  // 128 + 8 pad

typedef __bf16 bf16x8 __attribute__((ext_vector_type(8)));
typedef float f32x4 __attribute__((ext_vector_type(4)));

__device__ __forceinline__ f32x4 mfma16(bf16x8 a, bf16x8 b, f32x4 c) {
  return __builtin_amdgcn_mfma_f32_16x16x32_bf16(a, b, c, 0, 0, 0);
}
__device__ __forceinline__ float sigm(float x) { return 1.f / (1.f + __expf(-x)); }
__device__ __forceinline__ float tanh_(float x) { return 1.f - 2.f / (1.f + __expf(2.f * x)); }
__device__ __forceinline__ bf16x8 cvt8s(float4 lo, float4 hi, float s) {
  bf16x8 v;
  v[0] = (__bf16)(lo.x * s); v[1] = (__bf16)(lo.y * s);
  v[2] = (__bf16)(lo.z * s); v[3] = (__bf16)(lo.w * s);
  v[4] = (__bf16)(hi.x * s); v[5] = (__bf16)(hi.y * s);
  v[6] = (__bf16)(hi.z * s); v[7] = (__bf16)(hi.w * s);
  return v;
}
// fragment load: bf16 (staged weights) = one 16B load; f32 = 32B + inline cvt
__device__ __forceinline__ bf16x8 g8(const __bf16* p) { return *reinterpret_cast<const bf16x8*>(p); }
__device__ __forceinline__ bf16x8 g8(const float* p) {
  float4 lo = *(const float4*)p, hi = *(const float4*)(p + 4);
  return cvt8s(lo, hi, 1.f);
}
__device__ __forceinline__ bf16x8 zero8() {
  bf16x8 v;
#pragma unroll
  for (int i = 0; i < 8; ++i) v[i] = (__bf16)0.f;
  return v;
}

// ---------------- weight staging: 12 f32 matrices -> bf16 in ws ----------------
// elem offsets (all compile-time, all sizes % 8 == 0)
#define OW_EW1 0
#define OW_EW2 65536
#define OW_NW1 81920
#define OW_NW2 131072
#define OW_GW1 147456
#define OW_GW2 180224
#define OW_EWIH 196608
#define OW_EWHH 245760
#define OW_NWIH 294912
#define OW_NWHH 344064
#define OW_GWIH 393216
#define OW_GWHH 442368
#define OW_TOTAL 491520

struct W12 { const float* p[12]; };

__global__ __launch_bounds__(256) void cvt_kernel(W12 w, __bf16* __restrict__ out) {
  const int off[13] = {OW_EW1, OW_EW2, OW_NW1, OW_NW2, OW_GW1, OW_GW2,
                       OW_EWIH, OW_EWHH, OW_NWIH, OW_NWHH, OW_GWIH, OW_GWHH, OW_TOTAL};
  int e = (blockIdx.x * 256 + threadIdx.x) * 8;
  if (e >= OW_TOTAL) return;
  int s = 0;
#pragma unroll
  for (int i = 1; i < 12; ++i)
    if (e >= off[i]) s = i;
  const float* src = w.p[s] + (e - off[s]);
  float4 lo = *(const float4*)src, hi = *(const float4*)(src + 4);
  *reinterpret_cast<bf16x8*>(out + e) = cvt8s(lo, hi, 1.f);
}

__global__ void count_kernel(const int* __restrict__ dst, const int* __restrict__ batch,
                             int* __restrict__ dcnt, int* __restrict__ ncnt) {
  int i = blockIdx.x * 256 + threadIdx.x;
  if (i < NE) atomicAdd(&dcnt[dst[i]], 1);
  if (i < NN) atomicAdd(&ncnt[batch[i]], 1);
}

// ---------------- edge model: MLP(4H->H->H) + GRU, per-wave M=32 ----------------
template <typename WT>
__global__ __launch_bounds__(256, 2) void edge_kernel(
    const float* __restrict__ x, const int* __restrict__ ei,
    float* __restrict__ ea, const float* __restrict__ u, const int* __restrict__ batch,
    const WT* __restrict__ w1, const float* __restrict__ b1,
    const WT* __restrict__ w2, const float* __restrict__ b2,
    const WT* __restrict__ wih, const WT* __restrict__ whh,
    const float* __restrict__ bih, const float* __restrict__ bhh,
    float* __restrict__ agg, int ws_ok) {
  __shared__ __bf16 lds[4][32 * LROW];
  const int* src = ei;
  const int* dst = ei + NE;
  const int wave = threadIdx.x >> 6, lane = threadIdx.x & 63;
  const int lm = lane & 15, quad = lane >> 4;
  const long base = ((long)blockIdx.x * 4 + wave) * 32;
  __bf16* myl = lds[wave];

  long tA0 = base + lm;      const int eA0 = (int)(tA0 < NE ? tA0 : NE - 1);
  long tA1 = base + 16 + lm; const int eA1 = (int)(tA1 < NE ? tA1 : NE - 1);
  const int s0 = src[eA0], s1 = src[eA1];
  const int d0 = dst[eA0], d1 = dst[eA1];
  const int g0 = batch[s0], g1 = batch[s1];

  // ---- layer 1: K = 512 over 4 gathered segments ----
  f32x4 acc[8][2] = {};
  bf16x8 ah0[4], ah1[4];  // edge_attr A-frags, reused for GRU h-path
  for (int seg = 0; seg < 4; ++seg) {
    const float *p0, *p1;
    if (seg == 0)      { p0 = x + (size_t)s0 * H;   p1 = x + (size_t)s1 * H; }
    else if (seg == 1) { p0 = x + (size_t)d0 * H;   p1 = x + (size_t)d1 * H; }
    else if (seg == 2) { p0 = ea + (size_t)eA0 * H; p1 = ea + (size_t)eA1 * H; }
    else               { p0 = u + (size_t)g0 * H;   p1 = u + (size_t)g1 * H; }
#pragma unroll
    for (int ss = 0; ss < 4; ++ss) {
      const int kk = ss * 32 + quad * 8;
      bf16x8 a0 = g8(p0 + kk), a1 = g8(p1 + kk);
      if (seg == 2) { ah0[ss] = a0; ah1[ss] = a1; }
#pragma unroll
      for (int n = 0; n < 8; ++n) {
        bf16x8 bf = g8(w1 + (n * 16 + lm) * 512 + seg * 128 + kk);
        acc[n][0] = mfma16(a0, bf, acc[n][0]);
        acc[n][1] = mfma16(a1, bf, acc[n][1]);
      }
    }
  }
#pragma unroll
  for (int n = 0; n < 8; ++n) {
    const float bb = b1[n * 16 + lm];
#pragma unroll
    for (int sub = 0; sub < 2; ++sub)
#pragma unroll
      for (int r = 0; r < 4; ++r) {
        float v = fmaxf(acc[n][sub][r] + bb, 0.f);
        myl[(sub * 16 + quad * 4 + r) * LROW + n * 16 + lm] = (__bf16)v;
      }
  }
  __syncthreads();
  // ---- layer 2 ----
  bf16x8 a20[4], a21[4];
#pragma unroll
  for (int ss = 0; ss < 4; ++ss) {
    a20[ss] = g8(myl + lm * LROW + ss * 32 + quad * 8);
    a21[ss] = g8(myl + (16 + lm) * LROW + ss * 32 + quad * 8);
  }
  f32x4 acc2[8][2] = {};
#pragma unroll
  for (int ss = 0; ss < 4; ++ss) {
    const int kk = ss * 32 + quad * 8;
#pragma unroll
    for (int n = 0; n < 8; ++n) {
      bf16x8 bf = g8(w2 + (n * 16 + lm) * H + kk);
      acc2[n][0] = mfma16(a20[ss], bf, acc2[n][0]);
      acc2[n][1] = mfma16(a21[ss], bf, acc2[n][1]);
    }
  }
  __syncthreads();
#pragma unroll
  for (int n = 0; n < 8; ++n) {
    const float bb = b2[n * 16 + lm];
#pragma unroll
    for (int sub = 0; sub < 2; ++sub)
#pragma unroll
      for (int r = 0; r < 4; ++r)
        myl[(sub * 16 + quad * 4 + r) * LROW + n * 16 + lm] = (__bf16)(acc2[n][sub][r] + bb);
  }
  __syncthreads();
  // ---- GRU ----
  bf16x8 ao0[4], ao1[4];
#pragma unroll
  for (int ss = 0; ss < 4; ++ss) {
    ao0[ss] = g8(myl + lm * LROW + ss * 32 + quad * 8);
    ao1[ss] = g8(myl + (16 + lm) * LROW + ss * 32 + quad * 8);
  }
  int erow[2][4], drow[2][4];
#pragma unroll
  for (int sub = 0; sub < 2; ++sub)
#pragma unroll
    for (int r = 0; r < 4; ++r) {
      long e = base + sub * 16 + quad * 4 + r;
      int ec = (int)(e < NE ? e : NE - 1);
      erow[sub][r] = ec;
      drow[sub][r] = dst[ec];
    }
#pragma unroll 2
  for (int n = 0; n < 8; ++n) {
    f32x4 air[2] = {}, aiz[2] = {}, aig[2] = {};
    f32x4 ahr[2] = {}, ahz[2] = {}, ahg[2] = {};
    const int wr0 = (n * 16 + lm) * H;
#pragma unroll
    for (int ss = 0; ss < 4; ++ss) {
      const int kk = ss * 32 + quad * 8;
      bf16x8 wr = g8(wih + wr0 + kk);
      bf16x8 wz = g8(wih + wr0 + 128 * H + kk);
      bf16x8 wg = g8(wih + wr0 + 256 * H + kk);
      air[0] = mfma16(ao0[ss], wr, air[0]); air[1] = mfma16(ao1[ss], wr, air[1]);
      aiz[0] = mfma16(ao0[ss], wz, aiz[0]); aiz[1] = mfma16(ao1[ss], wz, aiz[1]);
      aig[0] = mfma16(ao0[ss], wg, aig[0]); aig[1] = mfma16(ao1[ss], wg, aig[1]);
      bf16x8 vr = g8(whh + wr0 + kk);
      bf16x8 vz = g8(whh + wr0 + 128 * H + kk);
      bf16x8 vg = g8(whh + wr0 + 256 * H + kk);
      ahr[0] = mfma16(ah0[ss], vr, ahr[0]); ahr[1] = mfma16(ah1[ss], vr, ahr[1]);
      ahz[0] = mfma16(ah0[ss], vz, ahz[0]); ahz[1] = mfma16(ah1[ss], vz, ahz[1]);
      ahg[0] = mfma16(ah0[ss], vg, ahg[0]); ahg[1] = mfma16(ah1[ss], vg, ahg[1]);
    }
    const int c = n * 16 + lm;
    const float bir = bih[c], biz = bih[c + 128], big = bih[c + 256];
    const float bhr = bhh[c], bhz = bhh[c + 128], bhg = bhh[c + 256];
#pragma unroll
    for (int sub = 0; sub < 2; ++sub)
#pragma unroll
      for (int r = 0; r < 4; ++r) {
        float rg = sigm(air[sub][r] + bir + ahr[sub][r] + bhr);
        float zg = sigm(aiz[sub][r] + biz + ahz[sub][r] + bhz);
        float ng = tanh_(aig[sub][r] + big + rg * (ahg[sub][r] + bhg));
        int e = erow[sub][r];
        float hold = ea[(size_t)e * H + c];
        float hnew = (1.f - zg) * ng + zg * hold;
        if (base + sub * 16 + quad * 4 + r < NE) {
          ea[(size_t)e * H + c] = hnew;
          if (ws_ok) atomicAdd(&agg[drow[sub][r] * H + c], hnew);
        }
      }
  }
}

// ---------------- node model: MLP(3H->H->H) + GRU ----------------
template <typename WT>
__global__ __launch_bounds__(256, 2) void node_kernel(
    float* __restrict__ x, const float* __restrict__ u, const int* __restrict__ batch,
    const float* __restrict__ agg, const int* __restrict__ dcnt,
    const WT* __restrict__ w1, const float* __restrict__ b1,
    const WT* __restrict__ w2, const float* __restrict__ b2,
    const WT* __restrict__ wih, const WT* __restrict__ whh,
    const float* __restrict__ bih, const float* __restrict__ bhh,
    float* __restrict__ xsum, int ws_ok) {
  __shared__ __bf16 lds[4][32 * LROW];
  const int wave = threadIdx.x >> 6, lane = threadIdx.x & 63;
  const int lm = lane & 15, quad = lane >> 4;
  const long base = ((long)blockIdx.x * 4 + wave) * 32;
  __bf16* myl = lds[wave];

  long tA0 = base + lm;      const int iA0 = (int)(tA0 < NN ? tA0 : NN - 1);
  long tA1 = base + 16 + lm; const int iA1 = (int)(tA1 < NN ? tA1 : NN - 1);
  const int g0 = batch[iA0], g1 = batch[iA1];
  const float inv0 = ws_ok ? 1.f / (float)max(dcnt[iA0], 1) : 1.f;
  const float inv1 = ws_ok ? 1.f / (float)max(dcnt[iA1], 1) : 1.f;

  f32x4 acc[8][2] = {};
  bf16x8 ah0[4], ah1[4];
  for (int seg = 0; seg < 3; ++seg) {
#pragma unroll
    for (int ss = 0; ss < 4; ++ss) {
      const int kk = ss * 32 + quad * 8;
      bf16x8 a0, a1;
      if (seg == 0) {
        a0 = g8(x + (size_t)iA0 * H + kk); a1 = g8(x + (size_t)iA1 * H + kk);
        ah0[ss] = a0; ah1[ss] = a1;
      } else if (seg == 1) {
        if (ws_ok) {
          float4 lo0 = *(const float4*)(agg + iA0 * H + kk);
          float4 hi0 = *(const float4*)(agg + iA0 * H + kk + 4);
          float4 lo1 = *(const float4*)(agg + iA1 * H + kk);
          float4 hi1 = *(const float4*)(agg + iA1 * H + kk + 4);
          a0 = cvt8s(lo0, hi0, inv0); a1 = cvt8s(lo1, hi1, inv1);
        } else {
          a0 = zero8(); a1 = zero8();
        }
      } else {
        a0 = g8(u + (size_t)g0 * H + kk); a1 = g8(u + (size_t)g1 * H + kk);
      }
#pragma unroll
      for (int n = 0; n < 8; ++n) {
        bf16x8 bf = g8(w1 + (n * 16 + lm) * 384 + seg * 128 + kk);
        acc[n][0] = mfma16(a0, bf, acc[n][0]);
        acc[n][1] = mfma16(a1, bf, acc[n][1]);
      }
    }
  }
#pragma unroll
  for (int n = 0; n < 8; ++n) {
    const float bb = b1[n * 16 + lm];
#pragma unroll
    for (int sub = 0; sub < 2; ++sub)
#pragma unroll
      for (int r = 0; r < 4; ++r) {
        float v = fmaxf(acc[n][sub][r] + bb, 0.f);
        myl[(sub * 16 + quad * 4 + r) * LROW + n * 16 + lm] = (__bf16)v;
      }
  }
  __syncthreads();
  bf16x8 a20[4], a21[4];
#pragma unroll
  for (int ss = 0; ss < 4; ++ss) {
    a20[ss] = g8(myl + lm * LROW + ss * 32 + quad * 8);
    a21[ss] = g8(myl + (16 + lm) * LROW + ss * 32 + quad * 8);
  }
  f32x4 acc2[8][2] = {};
#pragma unroll
  for (int ss = 0; ss < 4; ++ss) {
    const int kk = ss * 32 + quad * 8;
#pragma unroll
    for (int n = 0; n < 8; ++n) {
      bf16x8 bf = g8(w2 + (n * 16 + lm) * H + kk);
      acc2[n][0] = mfma16(a20[ss], bf, acc2[n][0]);
      acc2[n][1] = mfma16(a21[ss], bf, acc2[n][1]);
    }
  }
  __syncthreads();
#pragma unroll
  for (int n = 0; n < 8; ++n) {
    const float bb = b2[n * 16 + lm];
#pragma unroll
    for (int sub = 0; sub < 2; ++sub)
#pragma unroll
      for (int r = 0; r < 4; ++r)
        myl[(sub * 16 + quad * 4 + r) * LROW + n * 16 + lm] = (__bf16)(acc2[n][sub][r] + bb);
  }
  __syncthreads();
  bf16x8 ao0[4], ao1[4];
#pragma unroll
  for (int ss = 0; ss < 4; ++ss) {
    ao0[ss] = g8(myl + lm * LROW + ss * 32 + quad * 8);
    ao1[ss] = g8(myl + (16 + lm) * LROW + ss * 32 + quad * 8);
  }
  int irow[2][4], brow[2][4];
#pragma unroll
  for (int sub = 0; sub < 2; ++sub)
#pragma unroll
    for (int r = 0; r < 4; ++r) {
      long i = base + sub * 16 + quad * 4 + r;
      int ic = (int)(i < NN ? i : NN - 1);
      irow[sub][r] = ic;
      brow[sub][r] = batch[ic];
    }
#pragma unroll 2
  for (int n = 0; n < 8; ++n) {
    f32x4 air[2] = {}, aiz[2] = {}, aig[2] = {};
    f32x4 ahr[2] = {}, ahz[2] = {}, ahg[2] = {};
    const int wr0 = (n * 16 + lm) * H;
#pragma unroll
    for (int ss = 0; ss < 4; ++ss) {
      const int kk = ss * 32 + quad * 8;
      bf16x8 wr = g8(wih + wr0 + kk);
      bf16x8 wz = g8(wih + wr0 + 128 * H + kk);
      bf16x8 wg = g8(wih + wr0 + 256 * H + kk);
      air[0] = mfma16(ao0[ss], wr, air[0]); air[1] = mfma16(ao1[ss], wr, air[1]);
      aiz[0] = mfma16(ao0[ss], wz, aiz[0]); aiz[1] = mfma16(ao1[ss], wz, aiz[1]);
      aig[0] = mfma16(ao0[ss], wg, aig[0]); aig[1] = mfma16(ao1[ss], wg, aig[1]);
      bf16x8 vr = g8(whh + wr0 + kk);
      bf16x8 vz = g8(whh + wr0 + 128 * H + kk);
      bf16x8 vg = g8(whh + wr0 + 256 * H + kk);
      ahr[0] = mfma16(ah0[ss], vr, ahr[0]); ahr[1] = mfma16(ah1[ss], vr, ahr[1]);
      ahz[0] = mfma16(ah0[ss], vz, ahz[0]); ahz[1] = mfma16(ah1[ss], vz, ahz[1]);
      ahg[0] = mfma16(ah0[ss], vg, ahg[0]); ahg[1] = mfma16(ah1[ss], vg, ahg[1]);
    }
    const int c = n * 16 + lm;
    const float bir = bih[c], biz = bih[c + 128], big = bih[c + 256];
    const float bhr = bhh[c], bhz = bhh[c + 128], bhg = bhh[c + 256];
#pragma unroll
    for (int sub = 0; sub < 2; ++sub)
#pragma unroll
      for (int r = 0; r < 4; ++r) {
        float rg = sigm(air[sub][r] + bir + ahr[sub][r] + bhr);
        float zg = sigm(aiz[sub][r] + biz + ahz[sub][r] + bhz);
        float ng = tanh_(aig[sub][r] + big + rg * (ahg[sub][r] + bhg));
        int i = irow[sub][r];
        float hold = x[(size_t)i * H + c];
        float hnew = (1.f - zg) * ng + zg * hold;
        if (base + sub * 16 + quad * 4 + r < NN) {
          x[(size_t)i * H + c] = hnew;
          if (ws_ok) atomicAdd(&xsum[brow[sub][r] * H + c], hnew);
        }
      }
  }
}

// ---------------- global model: MLP(2H->H->H) + GRU, 1 block ----------------
template <typename WT>
__global__ __launch_bounds__(256) void glob_kernel(
    float* __restrict__ u, const float* __restrict__ xsum, const int* __restrict__ ncnt,
    const WT* __restrict__ w1, const float* __restrict__ b1,
    const WT* __restrict__ w2, const float* __restrict__ b2,
    const WT* __restrict__ wih, const WT* __restrict__ whh,
    const float* __restrict__ bih, const float* __restrict__ bhh,
    float* __restrict__ out, int t, int ws_ok) {
  __shared__ __bf16 lds[4][16 * LROW];
  const int wave = threadIdx.x >> 6, lane = threadIdx.x & 63;
  const int lm = lane & 15, quad = lane >> 4;
  __bf16* myl = lds[wave];
  const int row = wave * 16 + lm;
  const float inv = ws_ok ? 1.f / fmaxf((float)ncnt[row], 1.f) : 1.f;

  f32x4 acc[8] = {};
  bf16x8 ah[4];
#pragma unroll
  for (int seg = 0; seg < 2; ++seg) {
#pragma unroll
    for (int ss = 0; ss < 4; ++ss) {
      const int kk = ss * 32 + quad * 8;
      bf16x8 a;
      if (seg == 0) {
        a = g8(u + row * H + kk);
        ah[ss] = a;
      } else if (ws_ok) {
        float4 lo = *(const float4*)(xsum + row * H + kk);
        float4 hi = *(const float4*)(xsum + row * H + kk + 4);
        a = cvt8s(lo, hi, inv);
      } else {
        a = zero8();
      }
#pragma unroll
      for (int n = 0; n < 8; ++n) {
        bf16x8 bf = g8(w1 + (n * 16 + lm) * 256 + seg * 128 + kk);
        acc[n] = mfma16(a, bf, acc[n]);
      }
    }
  }
#pragma unroll
  for (int n = 0; n < 8; ++n) {
    const float bb = b1[n * 16 + lm];
#pragma unroll
    for (int r = 0; r < 4; ++r)
      myl[(quad * 4 + r) * LROW + n * 16 + lm] = (__bf16)fmaxf(acc[n][r] + bb, 0.f);
  }
  __syncthreads();
  bf16x8 a2[4];
#pragma unroll
  for (int ss = 0; ss < 4; ++ss) a2[ss] = g8(myl + lm * LROW + ss * 32 + quad * 8);
  f32x4 acc2[8] = {};
#pragma unroll
  for (int ss = 0; ss < 4; ++ss) {
    const int kk = ss * 32 + quad * 8;
#pragma unroll
    for (int n = 0; n < 8; ++n) {
      bf16x8 bf = g8(w2 + (n * 16 + lm) * H + kk);
      acc2[n] = mfma16(a2[ss], bf, acc2[n]);
    }
  }
  __syncthreads();
#pragma unroll
  for (int n = 0; n < 8; ++n) {
    const float bb = b2[n * 16 + lm];
#pragma unroll
    for (int r = 0; r < 4; ++r)
      myl[(quad * 4 + r) * LROW + n * 16 + lm] = (__bf16)(acc2[n][r] + bb);
  }
  __syncthreads();
  bf16x8 ao[4];
#pragma unroll
  for (int ss = 0; ss < 4; ++ss) ao[ss] = g8(myl + lm * LROW + ss * 32 + quad * 8);
  for (int n = 0; n < 8; ++n) {
    f32x4 air = {}, aiz = {}, aig = {}, ahr = {}, ahz = {}, ahg = {};
    const int wr0 = (n * 16 + lm) * H;
#pragma unroll
    for (int ss = 0; ss < 4; ++ss) {
      const int kk = ss * 32 + quad * 8;
      air = mfma16(ao[ss], g8(wih + wr0 + kk), air);
      aiz = mfma16(ao[ss], g8(wih + wr0 + 128 * H + kk), aiz);
      aig = mfma16(ao[ss], g8(wih + wr0 + 256 * H + kk), aig);
      ahr = mfma16(ah[ss], g8(whh + wr0 + kk), ahr);
      ahz = mfma16(ah[ss], g8(whh + wr0 + 128 * H + kk), ahz);
      ahg = mfma16(ah[ss], g8(whh + wr0 + 256 * H + kk), ahg);
    }
    const int c = n * 16 + lm;
    const float bir = bih[c], biz = bih[c + 128], big = bih[c + 256];
    const float bhr = bhh[c], bhz = bhh[c + 128], bhg = bhh[c + 256];
#pragma unroll
    for (int r = 0; r < 4; ++r) {
      const int rowC = wave * 16 + quad * 4 + r;
      float rg = sigm(air[r] + bir + ahr[r] + bhr);
      float zg = sigm(aiz[r] + biz + ahz[r] + bhz);
      float ng = tanh_(aig[r] + big + rg * (ahg[r] + bhg));
      float hold = u[rowC * H + c];
      float hnew = (1.f - zg) * ng + zg * hold;
      u[rowC * H + c] = hnew;
      out[(rowC * NSTEPS + t) * H + c] = hnew;
    }
  }
}

extern "C" void kernel_launch(void* const* d_in, const int* in_sizes, int n_in,
                              void* d_out, int out_size, void* d_ws, size_t ws_size,
                              hipStream_t stream) {
  float* x = (float*)d_in[0];
  const int* ei = (const int*)d_in[1];
  float* ea = (float*)d_in[2];
  float* u = (float*)d_in[3];
  const int* batch = (const int*)d_in[4];
  float* out = (float*)d_out;

  char* ws = (char*)d_ws;
  float* agg = (float*)ws;                                        // NN*H f32
  float* xsum = (float*)(ws + (size_t)NN * H * 4);                // NB*H f32
  int* dcnt = (int*)(ws + (size_t)NN * H * 4 + (size_t)NB * H * 4);
  int* ncnt = dcnt + NN;
  __bf16* wbuf = (__bf16*)(ws + (size_t)NN * H * 4 + (size_t)NB * H * 4 + (size_t)(NN + NB) * 4);
  const size_t need = (size_t)NN * H * 4 + (size_t)NB * H * 4 + (size_t)(NN + NB) * 4 +
                      (size_t)OW_TOTAL * 2;
  const int ws_ok = (ws_size >= need) ? 1 : 0;

  if (ws_ok) {
    W12 w;
    w.p[0] = (const float*)d_in[5];   // ew1
    w.p[1] = (const float*)d_in[7];   // ew2
    w.p[2] = (const float*)d_in[9];   // nw1
    w.p[3] = (const float*)d_in[11];  // nw2
    w.p[4] = (const float*)d_in[13];  // gw1
    w.p[5] = (const float*)d_in[15];  // gw2
    w.p[6] = (const float*)d_in[17];  // ewih
    w.p[7] = (const float*)d_in[18];  // ewhh
    w.p[8] = (const float*)d_in[21];  // nwih
    w.p[9] = (const float*)d_in[22];  // nwhh
    w.p[10] = (const float*)d_in[25]; // gwih
    w.p[11] = (const float*)d_in[26]; // gwhh
    cvt_kernel<<<(OW_TOTAL / 8 + 255) / 256, 256, 0, stream>>>(w, wbuf);
    hipMemsetAsync(dcnt, 0, (NN + NB) * sizeof(int), stream);
    count_kernel<<<(NE + 255) / 256, 256, 0, stream>>>(ei + NE, batch, dcnt, ncnt);
  }

  for (int t = 0; t < NSTEPS; ++t) {
    if (ws_ok) {
      hipMemsetAsync(agg, 0, (size_t)NN * H * sizeof(float), stream);
      hipMemsetAsync(xsum, 0, (size_t)NB * H * sizeof(float), stream);
      edge_kernel<__bf16><<<(NE + 127) / 128, 256, 0, stream>>>(
          x, ei, ea, u, batch,
          wbuf + OW_EW1, (const float*)d_in[6], wbuf + OW_EW2, (const float*)d_in[8],
          wbuf + OW_EWIH, wbuf + OW_EWHH, (const float*)d_in[19], (const float*)d_in[20],
          agg, 1);
      node_kernel<__bf16><<<(NN + 127) / 128, 256, 0, stream>>>(
          x, u, batch, agg, dcnt,
          wbuf + OW_NW1, (const float*)d_in[10], wbuf + OW_NW2, (const float*)d_in[12],
          wbuf + OW_NWIH, wbuf + OW_NWHH, (const float*)d_in[23], (const float*)d_in[24],
          xsum, 1);
      glob_kernel<__bf16><<<1, 256, 0, stream>>>(
          u, xsum, ncnt,
          wbuf + OW_GW1, (const float*)d_in[14], wbuf + OW_GW2, (const float*)d_in[16],
          wbuf + OW_GWIH, wbuf + OW_GWHH, (const float*)d_in[27], (const float*)d_in[28],
          out, t, 1);
    } else {
      // never-taken safety path: raw f32 weights, no aggregation workspace
      edge_kernel<float><<<(NE + 127) / 128, 256, 0, stream>>>(
          x, ei, ea, u, batch,
          (const float*)d_in[5], (const float*)d_in[6], (const float*)d_in[7], (const float*)d_in[8],
          (const float*)d_in[17], (const float*)d_in[18], (const float*)d_in[19], (const float*)d_in[20],
          agg, 0);
      node_kernel<float><<<(NN + 127) / 128, 256, 0, stream>>>(
          x, u, batch, agg, dcnt,
          (const float*)d_in[9], (const float*)d_in[10], (const float*)d_in[11], (const float*)d_in[12],
          (const float*)d_in[21], (const float*)d_in[22], (const float*)d_in[23], (const float*)d_in[24],
          xsum, 0);
      glob_kernel<float><<<1, 256, 0, stream>>>(
          u, xsum, ncnt,
          (const float*)d_in[13], (const float*)d_in[14], (const float*)d_in[15], (const float*)d_in[16],
          (const float*)d_in[25], (const float*)d_in[26], (const float*)d_in[27], (const float*)d_in[28],
          out, t, 0);
    }
  }
}